// Round 12
// baseline (185.332 us; speedup 1.0000x reference)
//
#include <hip/hip_runtime.h>

#define N_NODES 100000
#define N_EDGES 3200000
#define F_IN    128
#define HID     64
#define NGRAPH  64

#define NBUK    196        // ceil(100000 / 512) buckets of 512 nodes
#define BSHIFT  9
#define BCAP    18432      // mean 16384, sigma ~128 -> +16 sigma
#define CHUNK   2560       // 256 threads x 10 edges; 1250 * 2560 == 3.2M exactly
#define NBLK_A  1250
#define SLICES  8          // partB slices per bucket
#define NWORDS  3200       // 100000 bits -> 3125 words, padded
#define MAXDEG  96         // in-degree ~Poisson(32); P(>96) ~ 1e-19
#define NIDCAP  4096       // needed nodes ~2100
#define L2CAP   8192       // big-dst edges ~2048
#define NBLK_X  2048       // xaggtrans grid

// counters: [1]=l2 edge count, [2]=needed-node (nid) count

__device__ __forceinline__ bool is_big(int v, const int* __restrict__ batch) {
    return (v == N_NODES - 1) || (batch[v] != batch[v + 1]);
}
__device__ __forceinline__ float dinv_of(int degv) {
    return rsqrtf((float)(degv + 1));                // +1 self-loop
}

// Big nodes: set bigmask+nmask bits, assign nids 0..63.
__global__ void k_init(const int* __restrict__ batch, unsigned* __restrict__ bigmask,
                       unsigned* __restrict__ nmask, int* __restrict__ nid_of,
                       int* __restrict__ nlist, int* __restrict__ counters) {
    int v = blockIdx.x * 256 + threadIdx.x;
    if (v >= N_NODES) return;
    if (is_big(v, batch)) {
        atomicOr(&bigmask[v >> 5], 1u << (v & 31));
        atomicOr(&nmask[v >> 5], 1u << (v & 31));
        int p = atomicAdd(&counters[2], 1);          // exactly 64
        nid_of[v] = p;
        nlist[p]  = v;
    }
}

// Pass A: partition 2560 edges/block into 196 dst-range buckets.
// Per-wave hist -> shfl scan (2 barriers) -> LDS scatter -> coalesced write-out.
// Payload packs (src<<9)|(dst&511). Fused big-dst -> nmask mark + l2list.
// 1250 blocks (~4.9/CU) for load balance; LDS ~19 KB.
// NOTE (R10 post-mortem): do NOT fuse cross-kernel handoffs with
// __threadfence on gfx950 — device-scope fences drain per-XCD L2;
// kernel boundaries provide the ordering for free.
__global__ __launch_bounds__(256) void k_partA(const int* __restrict__ src,
        const int* __restrict__ dst, const unsigned* __restrict__ bigmask,
        unsigned* __restrict__ nmask, unsigned* __restrict__ plist,
        int* __restrict__ bcnt, int2* __restrict__ l2list, int* __restrict__ counters) {
    __shared__ unsigned staged[CHUNK];         // 10240 B, bucket-ordered payload
    __shared__ unsigned char sbkt[CHUNK];      // 2560 B, bucket id per slot
    __shared__ int hist4[4][NBUK];             // 3136 B
    __shared__ int startb[256];                // exclusive starts (NBUK padded)
    __shared__ int curb[NBUK], gbasea[NBUK];
    __shared__ int wsum[4];
    __shared__ int2 l2buf[64];
    __shared__ int l2n, l2base;                // ~19 KB total
    const int t = threadIdx.x;
    const int lane = t & 63;
    const int w = t >> 6;
    for (int i = t; i < NBUK; i += 256) {
        hist4[0][i] = 0; hist4[1][i] = 0; hist4[2][i] = 0; hist4[3][i] = 0;
    }
    if (t == 0) l2n = 0;
    __syncthreads();

    const int E0 = blockIdx.x * CHUNK;         // even
    const int2* s2 = (const int2*)(src + E0);
    const int2* d2 = (const int2*)(dst + E0);
    int vloc[10]; unsigned pk[10];
#pragma unroll
    for (int it = 0; it < 5; ++it) {
        int2 dd = d2[t + it * 256];
        int2 ss = s2[t + it * 256];
        int vv[2] = {dd.x, dd.y};
        int uu[2] = {ss.x, ss.y};
#pragma unroll
        for (int j = 0; j < 2; ++j) {
            int v = vv[j], u = uu[j];
            vloc[it * 2 + j] = v;
            pk[it * 2 + j] = ((unsigned)u << BSHIFT) | (unsigned)(v & 511);
            atomicAdd(&hist4[w][v >> BSHIFT], 1);
            if ((bigmask[v >> 5] >> (v & 31)) & 1) {      // L1-hot 12.8 KB table
                atomicOr(&nmask[u >> 5], 1u << (u & 31)); // ~2k total
                int p = atomicAdd(&l2n, 1);
                if (p < 64) l2buf[p] = make_int2(u, v);
            }
        }
    }
    __syncthreads();
    // bucket counts -> exclusive prefix: shfl scan within wave + cross-wave combine
    int c = 0;
    if (t < NBUK) c = hist4[0][t] + hist4[1][t] + hist4[2][t] + hist4[3][t];
    int sc = c;
#pragma unroll
    for (int off = 1; off < 64; off <<= 1) {
        int y = __shfl_up(sc, off, 64);
        if (lane >= off) sc += y;
    }
    if (lane == 63) wsum[w] = sc;
    __syncthreads();
    int pre = 0;
#pragma unroll
    for (int k = 0; k < 4; ++k) pre += (k < w) ? wsum[k] : 0;
    int excl = pre + sc - c;
    startb[t] = excl;
    if (t < NBUK) {
        curb[t]   = excl;
        gbasea[t] = atomicAdd(&bcnt[t], c);    // reserve global run
    }
    if (t == 0 && l2n > 0) {
        int ln = l2n; if (ln > 64) ln = 64;
        l2base = atomicAdd(&counters[1], ln);
    }
    __syncthreads();
    {
        int ln = l2n; if (ln > 64) ln = 64;
        for (int i = t; i < ln; i += 256) {
            int p = l2base + i;
            if (p < L2CAP) l2list[p] = l2buf[i];
        }
    }
#pragma unroll
    for (int it = 0; it < 10; ++it) {          // LDS scatter (cheap)
        int b = vloc[it] >> BSHIFT;
        int pos = atomicAdd(&curb[b], 1);
        staged[pos] = pk[it];
        sbkt[pos]   = (unsigned char)b;
    }
    __syncthreads();
    for (int i = t; i < CHUNK; i += 256) {     // coalesced run write-out
        int b = sbkt[i];
        int s = gbasea[b] + (i - startb[b]);
        if (s < BCAP) plist[(size_t)b * BCAP + s] = staged[i];
    }
}

// Assign nids to needed-but-not-big nodes: popcount + block scan, 1 atomic/block.
__global__ void k_buildnid(const unsigned* __restrict__ nmask,
                           const unsigned* __restrict__ bigmask,
                           int* __restrict__ nid_of, int* __restrict__ nlist,
                           int* __restrict__ counters) {
    int w = blockIdx.x * 256 + threadIdx.x;
    unsigned m = (w < NWORDS) ? (nmask[w] & ~bigmask[w]) : 0u;
    int c = __popc(m);
    __shared__ int sc[256];
    __shared__ int gbase;
    sc[threadIdx.x] = c;
    __syncthreads();
    for (int off = 1; off < 256; off <<= 1) {
        int t = (threadIdx.x >= off) ? sc[threadIdx.x - off] : 0;
        __syncthreads();
        sc[threadIdx.x] += t;
        __syncthreads();
    }
    if (threadIdx.x == 0) gbase = atomicAdd(&counters[2], sc[255]);
    __syncthreads();
    int p = gbase + sc[threadIdx.x] - c;             // exclusive offset
    while (m) {
        int b = __ffs(m) - 1; m &= m - 1;
        int v = w * 32 + b;
        if (p < NIDCAP) { nid_of[v] = p; nlist[p] = v; }
        p++;
    }
}

// Pass B: 8 slices per bucket (1568 blocks). Private 512-bin LDS histogram +
// CSR extraction (nmask probed via L1); coalesced atomic flush into deg[].
__global__ __launch_bounds__(256) void k_partB(const unsigned* __restrict__ plist,
        const int* __restrict__ bcnt, const unsigned* __restrict__ nmask,
        const int* __restrict__ nid_of, int* __restrict__ incnt,
        int* __restrict__ csr, int* __restrict__ deg) {
    __shared__ int bins[512];
    const int b = blockIdx.x / SLICES, s = blockIdx.x % SLICES;
    for (int i = threadIdx.x; i < 512; i += 256) bins[i] = 0;
    __syncthreads();
    int n = bcnt[b]; if (n > BCAP) n = BCAP;
    const int i0 = (int)((long)n * s / SLICES);
    const int i1 = (int)((long)n * (s + 1) / SLICES);
    const unsigned* lp = plist + (size_t)b * BCAP;
    const int lo = b << BSHIFT;
    for (int i = i0 + threadIdx.x; i < i1; i += 256) {
        unsigned e = lp[i];
        int local = (int)(e & 511u);
        atomicAdd(&bins[local], 1);
        int v = lo + local;
        if ((nmask[v >> 5] >> (v & 31)) & 1) {           // L1-hot probe
            int nid = nid_of[v];
            int slot = atomicAdd(&incnt[nid], 1);        // ~67k over ~2.1k ctrs
            if (slot < MAXDEG) csr[nid * MAXDEG + slot] = (int)(e >> BSHIFT);
        }
    }
    __syncthreads();
    for (int i = threadIdx.x; i < 512; i += 256) {       // coalesced flush
        int v = lo + i, c = bins[i];
        if (c > 0 && v < N_NODES) atomicAdd(&deg[v], c);
    }
}

// Fused: xagg (linearity: aggregate raw x rows) -> @W1 + b1 -> ReLU -> dot W2.
// One block per needed node; aggregate lives only in LDS. h2s is nid-indexed.
__global__ __launch_bounds__(256) void k_xaggtrans(const int* __restrict__ nlist,
        const int* __restrict__ incnt, const int* __restrict__ csr,
        const int* __restrict__ deg, const float* __restrict__ x,
        const float* __restrict__ W1, const float* __restrict__ b1,
        const float* __restrict__ W2, const int* __restrict__ counters,
        float* __restrict__ h2s) {
    __shared__ float4 sm[8][32];                     // 4 KB partials
    __shared__ float xaggL[F_IN];                    // 512 B aggregate
    __shared__ float p2[4 * HID];                    // 1 KB W1 partials
    int ncnt = counters[2]; if (ncnt > NIDCAP) ncnt = NIDCAP;
    const int tid = threadIdx.x;
    const int l = tid & 31, g = tid >> 5;            // phase-1 roles
    const int f = tid & 63, gg = tid >> 6;           // phase-2 roles
    for (int nid = blockIdx.x; nid < ncnt; nid += gridDim.x) {
        int v = nlist[nid];
        int m = incnt[nid]; if (m > MAXDEG) m = MAXDEG;
        const int* cs = csr + nid * MAXDEG;
        float4 acc = make_float4(0.f, 0.f, 0.f, 0.f);
        for (int j = g; j < m; j += 8) {
            int u = cs[j];                            // 32-lane broadcast
            float du = dinv_of(deg[u]);
            float4 xr = ((const float4*)(x + (size_t)u * F_IN))[l]; // 512B row
            acc.x += du * xr.x; acc.y += du * xr.y;
            acc.z += du * xr.z; acc.w += du * xr.w;
        }
        sm[g][l] = acc;
        __syncthreads();
        if (tid < 32) {                               // reduce + self-loop term
            float4 tot = make_float4(0.f, 0.f, 0.f, 0.f);
#pragma unroll
            for (int k = 0; k < 8; ++k) {
                float4 p = sm[k][tid];
                tot.x += p.x; tot.y += p.y; tot.z += p.z; tot.w += p.w;
            }
            float dv = dinv_of(deg[v]);
            float4 xv = ((const float4*)(x + (size_t)v * F_IN))[tid];
            float4 r;
            r.x = dv * tot.x + dv * dv * xv.x;
            r.y = dv * tot.y + dv * dv * xv.y;
            r.z = dv * tot.z + dv * dv * xv.z;
            r.w = dv * tot.w + dv * dv * xv.w;
            ((float4*)xaggL)[tid] = r;
        }
        __syncthreads();
        // phase 2: h1[f] = sum_k xaggL[k] * W1[k][f]; 4 k-slices of 32
        float a = 0.f;
#pragma unroll
        for (int k0 = 0; k0 < 32; ++k0) {
            int k = gg * 32 + k0;
            a += xaggL[k] * W1[(size_t)k * HID + f];  // coalesced, L1/L2-hot
        }
        p2[gg * HID + f] = a;
        __syncthreads();
        if (tid < HID) {
            float h = p2[tid] + p2[HID + tid] + p2[2 * HID + tid] + p2[3 * HID + tid] + b1[tid];
            float cc = fmaxf(h, 0.f) * W2[tid];
#pragma unroll
            for (int off = 32; off > 0; off >>= 1) cc += __shfl_down(cc, off, 64);
            if (tid == 0) h2s[nid] = cc;
        }
        __syncthreads();
    }
}

// layer-2 aggregation: single block, LDS accumulators, one clean write per graph
// (also absorbs out-zeroing: every out[g] is written exactly once).
__global__ __launch_bounds__(256) void k_agg2(const int2* __restrict__ l2list,
        const int* __restrict__ counters, const int* __restrict__ deg,
        const float* __restrict__ h2s, const int* __restrict__ batch,
        const int* __restrict__ nlist, const int* __restrict__ nid_of,
        const float* __restrict__ b2, float* __restrict__ out) {
    __shared__ float sacc[NGRAPH];
    const int tid = threadIdx.x;
    if (tid < NGRAPH) sacc[tid] = 0.f;
    __syncthreads();
    int n = counters[1]; if (n > L2CAP) n = L2CAP;
    for (int i = tid; i < n; i += 256) {
        int2 e = l2list[i];
        float dx = dinv_of(deg[e.x]);
        float dy = dinv_of(deg[e.y]);
        atomicAdd(&sacc[batch[e.y]], dx * dy * h2s[nid_of[e.x]]);  // LDS atomic
    }
    __syncthreads();
    if (tid < NGRAPH) {                              // big nodes have nid 0..63
        int v = nlist[tid];
        float di = dinv_of(deg[v]);
        out[batch[v]] = sacc[batch[v]] + di * di * h2s[tid] + b2[0];
    }
}

extern "C" void kernel_launch(void* const* d_in, const int* in_sizes, int n_in,
                              void* d_out, int out_size, void* d_ws, size_t ws_size,
                              hipStream_t stream) {
    const float* x     = (const float*)d_in[0];
    const int*   eidx  = (const int*)d_in[1];
    const int*   src   = eidx;
    const int*   dst   = eidx + N_EDGES;
    const int*   batch = (const int*)d_in[2];
    const float* W1    = (const float*)d_in[3];
    const float* b1    = (const float*)d_in[4];
    const float* W2    = (const float*)d_in[5];
    const float* b2    = (const float*)d_in[6];
    float*       out   = (float*)d_out;

    // ---- workspace layout: zeroed region first (~0.45 MB) ----
    char* ws = (char*)d_ws;
    size_t off = 0;
    int*      counters = (int*)(ws + off);      off += 256;
    int*      bcnt     = (int*)(ws + off);      off += 1024;               // NBUK padded
    unsigned* nmask    = (unsigned*)(ws + off); off += NWORDS * 4;         // 12.8 KB
    unsigned* bigmask  = (unsigned*)(ws + off); off += NWORDS * 4;
    int*      incnt    = (int*)(ws + off);      off += NIDCAP * 4;
    int*      deg      = (int*)(ws + off);      off += (size_t)N_NODES * 4; // 0.4 MB
    size_t zero_bytes = off;
    int*      nid_of   = (int*)(ws + off);      off += (size_t)N_NODES * 4;
    int*      nlist    = (int*)(ws + off);      off += (size_t)NIDCAP * 4;
    float*    h2s      = (float*)(ws + off);    off += (size_t)NIDCAP * 4;
    int2*     l2list   = (int2*)(ws + off);     off += (size_t)L2CAP * 8;
    int*      csr      = (int*)(ws + off);      off += (size_t)NIDCAP * MAXDEG * 4; // 1.6 MB
    unsigned* plist    = (unsigned*)(ws + off); off += (size_t)NBUK * BCAP * 4;     // 14.5 MB
    if (off > ws_size) return;  // visible validation failure if ws too small

    hipMemsetAsync(d_ws, 0, zero_bytes, stream);

    const int BN = (N_NODES + 255) / 256;

    k_init<<<BN, 256, 0, stream>>>(batch, bigmask, nmask, nid_of, nlist, counters);
    k_partA<<<NBLK_A, 256, 0, stream>>>(src, dst, bigmask, nmask, plist, bcnt, l2list, counters);
    k_buildnid<<<(NWORDS + 255) / 256, 256, 0, stream>>>(nmask, bigmask, nid_of, nlist, counters);
    k_partB<<<NBUK * SLICES, 256, 0, stream>>>(plist, bcnt, nmask, nid_of, incnt, csr, deg);
    k_xaggtrans<<<NBLK_X, 256, 0, stream>>>(nlist, incnt, csr, deg, x, W1, b1, W2, counters, h2s);
    k_agg2<<<1, 256, 0, stream>>>(l2list, counters, deg, h2s, batch, nlist, nid_of, b2, out);
}

// Round 13
// 170.011 us; speedup vs baseline: 1.0901x; 1.0901x over previous
//
#include <hip/hip_runtime.h>

#define N_NODES 100000
#define N_EDGES 3200000
#define F_IN    128
#define HID     64
#define NGRAPH  64

#define NBUK    196        // ceil(100000 / 512) buckets of 512 nodes
#define BSHIFT  9
#define BCAP    18432      // mean 16384, sigma ~128 -> +16 sigma
#define CHUNK   5120       // 256 threads x 20 edges; 625 * 5120 == 3.2M exactly
#define NBLK_A  625
#define SLICES  8          // partB slices per bucket
#define NWORDS  3200       // 100000 bits -> 3125 words, padded
#define MAXDEG  96         // in-degree ~Poisson(32); P(>96) ~ 1e-19
#define NIDCAP  4096       // needed nodes ~2100
#define L2CAP   8192       // big-dst edges ~2048
#define NBLK_X  2048       // xaggtrans grid

// counters: [1]=l2 edge count, [2]=needed-node (nid) count

__device__ __forceinline__ bool is_big(int v, const int* __restrict__ batch) {
    return (v == N_NODES - 1) || (batch[v] != batch[v + 1]);
}
__device__ __forceinline__ float dinv_of(int degv) {
    return rsqrtf((float)(degv + 1));                // +1 self-loop
}

// Big nodes: set bigmask+nmask bits, assign nids 0..63. Also zero d_out.
__global__ void k_init(const int* __restrict__ batch, unsigned* __restrict__ bigmask,
                       unsigned* __restrict__ nmask, int* __restrict__ nid_of,
                       int* __restrict__ nlist, int* __restrict__ counters,
                       float* __restrict__ out) {
    if (blockIdx.x == 0 && threadIdx.x < NGRAPH) out[threadIdx.x] = 0.f;
    int v = blockIdx.x * 256 + threadIdx.x;
    if (v >= N_NODES) return;
    if (is_big(v, batch)) {
        atomicOr(&bigmask[v >> 5], 1u << (v & 31));
        atomicOr(&nmask[v >> 5], 1u << (v & 31));
        int p = atomicAdd(&counters[2], 1);          // exactly 64
        nid_of[v] = p;
        nlist[p]  = v;
    }
}

// Pass A: partition 5120 edges/block into 196 dst-range buckets.
// Per-wave hist -> shfl scan (2 barriers) -> LDS scatter -> coalesced write-out.
// Payload packs (src<<9)|(dst&511). Fused big-dst -> nmask mark + l2list.
// NOTE (R12 post-mortem): partA is latency-bound at ~41us across three
// structurally different implementations (direct scatter / staged sort /
// shfl-scan; 625 vs 1250 blocks) — do not re-tune; this is its plateau.
// NOTE (R10 post-mortem): do NOT fuse cross-kernel handoffs with
// __threadfence on gfx950 — device-scope fences drain per-XCD L2;
// kernel boundaries provide the ordering for free.
__global__ __launch_bounds__(256) void k_partA(const int* __restrict__ src,
        const int* __restrict__ dst, const unsigned* __restrict__ bigmask,
        unsigned* __restrict__ nmask, unsigned* __restrict__ plist,
        int* __restrict__ bcnt, int2* __restrict__ l2list, int* __restrict__ counters) {
    __shared__ unsigned staged[CHUNK];         // 20480 B, bucket-ordered payload
    __shared__ unsigned char sbkt[CHUNK];      // 5120 B, bucket id per slot
    __shared__ int hist4[4][NBUK];             // 3136 B
    __shared__ int startb[256];                // exclusive starts (NBUK padded)
    __shared__ int curb[NBUK], gbasea[NBUK];
    __shared__ int wsum[4];
    __shared__ int2 l2buf[64];
    __shared__ int l2n, l2base;                // ~32 KB -> 5 blocks/CU
    const int t = threadIdx.x;
    const int lane = t & 63;
    const int w = t >> 6;
    for (int i = t; i < NBUK; i += 256) {
        hist4[0][i] = 0; hist4[1][i] = 0; hist4[2][i] = 0; hist4[3][i] = 0;
    }
    if (t == 0) l2n = 0;
    __syncthreads();

    const int E0 = blockIdx.x * CHUNK;         // multiple of 4
    const int4* s4 = (const int4*)(src + E0);
    const int4* d4 = (const int4*)(dst + E0);
    int vloc[20]; unsigned pk[20];
#pragma unroll
    for (int it = 0; it < 5; ++it) {
        int4 dd = d4[t + it * 256];
        int4 ss = s4[t + it * 256];
        int vv[4] = {dd.x, dd.y, dd.z, dd.w};
        int uu[4] = {ss.x, ss.y, ss.z, ss.w};
#pragma unroll
        for (int j = 0; j < 4; ++j) {
            int v = vv[j], u = uu[j];
            vloc[it * 4 + j] = v;
            pk[it * 4 + j] = ((unsigned)u << BSHIFT) | (unsigned)(v & 511);
            atomicAdd(&hist4[w][v >> BSHIFT], 1);
            if ((bigmask[v >> 5] >> (v & 31)) & 1) {      // L1-hot 12.8 KB table
                atomicOr(&nmask[u >> 5], 1u << (u & 31)); // ~2k total
                int p = atomicAdd(&l2n, 1);
                if (p < 64) l2buf[p] = make_int2(u, v);
            }
        }
    }
    __syncthreads();
    // bucket counts -> exclusive prefix: shfl scan within wave + cross-wave combine
    int c = 0;
    if (t < NBUK) c = hist4[0][t] + hist4[1][t] + hist4[2][t] + hist4[3][t];
    int sc = c;
#pragma unroll
    for (int off = 1; off < 64; off <<= 1) {
        int y = __shfl_up(sc, off, 64);
        if (lane >= off) sc += y;
    }
    if (lane == 63) wsum[w] = sc;
    __syncthreads();
    int pre = 0;
#pragma unroll
    for (int k = 0; k < 4; ++k) pre += (k < w) ? wsum[k] : 0;
    int excl = pre + sc - c;
    startb[t] = excl;
    if (t < NBUK) {
        curb[t]   = excl;
        gbasea[t] = atomicAdd(&bcnt[t], c);    // reserve global run
    }
    if (t == 0 && l2n > 0) {
        int ln = l2n; if (ln > 64) ln = 64;
        l2base = atomicAdd(&counters[1], ln);
    }
    __syncthreads();
    {
        int ln = l2n; if (ln > 64) ln = 64;
        for (int i = t; i < ln; i += 256) {
            int p = l2base + i;
            if (p < L2CAP) l2list[p] = l2buf[i];
        }
    }
#pragma unroll
    for (int it = 0; it < 20; ++it) {          // LDS scatter (cheap)
        int b = vloc[it] >> BSHIFT;
        int pos = atomicAdd(&curb[b], 1);
        staged[pos] = pk[it];
        sbkt[pos]   = (unsigned char)b;
    }
    __syncthreads();
    for (int i = t; i < CHUNK; i += 256) {     // coalesced run write-out
        int b = sbkt[i];
        int s = gbasea[b] + (i - startb[b]);
        if (s < BCAP) plist[(size_t)b * BCAP + s] = staged[i];
    }
}

// Assign nids to needed-but-not-big nodes: popcount + block scan, 1 atomic/block.
__global__ void k_buildnid(const unsigned* __restrict__ nmask,
                           const unsigned* __restrict__ bigmask,
                           int* __restrict__ nid_of, int* __restrict__ nlist,
                           int* __restrict__ counters) {
    int w = blockIdx.x * 256 + threadIdx.x;
    unsigned m = (w < NWORDS) ? (nmask[w] & ~bigmask[w]) : 0u;
    int c = __popc(m);
    __shared__ int sc[256];
    __shared__ int gbase;
    sc[threadIdx.x] = c;
    __syncthreads();
    for (int off = 1; off < 256; off <<= 1) {
        int t = (threadIdx.x >= off) ? sc[threadIdx.x - off] : 0;
        __syncthreads();
        sc[threadIdx.x] += t;
        __syncthreads();
    }
    if (threadIdx.x == 0) gbase = atomicAdd(&counters[2], sc[255]);
    __syncthreads();
    int p = gbase + sc[threadIdx.x] - c;             // exclusive offset
    while (m) {
        int b = __ffs(m) - 1; m &= m - 1;
        int v = w * 32 + b;
        if (p < NIDCAP) { nid_of[v] = p; nlist[p] = v; }
        p++;
    }
}

// Pass B: 8 slices per bucket (1568 blocks). Private 512-bin LDS histogram +
// CSR extraction (nmask probed via L1); coalesced atomic flush into deg[].
__global__ __launch_bounds__(256) void k_partB(const unsigned* __restrict__ plist,
        const int* __restrict__ bcnt, const unsigned* __restrict__ nmask,
        const int* __restrict__ nid_of, int* __restrict__ incnt,
        int* __restrict__ csr, int* __restrict__ deg) {
    __shared__ int bins[512];
    const int b = blockIdx.x / SLICES, s = blockIdx.x % SLICES;
    for (int i = threadIdx.x; i < 512; i += 256) bins[i] = 0;
    __syncthreads();
    int n = bcnt[b]; if (n > BCAP) n = BCAP;
    const int i0 = (int)((long)n * s / SLICES);
    const int i1 = (int)((long)n * (s + 1) / SLICES);
    const unsigned* lp = plist + (size_t)b * BCAP;
    const int lo = b << BSHIFT;
    for (int i = i0 + threadIdx.x; i < i1; i += 256) {
        unsigned e = lp[i];
        int local = (int)(e & 511u);
        atomicAdd(&bins[local], 1);
        int v = lo + local;
        if ((nmask[v >> 5] >> (v & 31)) & 1) {           // L1-hot probe
            int nid = nid_of[v];
            int slot = atomicAdd(&incnt[nid], 1);        // ~67k over ~2.1k ctrs
            if (slot < MAXDEG) csr[nid * MAXDEG + slot] = (int)(e >> BSHIFT);
        }
    }
    __syncthreads();
    for (int i = threadIdx.x; i < 512; i += 256) {       // coalesced flush
        int v = lo + i, c = bins[i];
        if (c > 0 && v < N_NODES) atomicAdd(&deg[v], c);
    }
}

// Fused: xagg (linearity: aggregate raw x rows) -> @W1 + b1 -> ReLU -> dot W2.
// One block per needed node; aggregate lives only in LDS. h2s is nid-indexed.
__global__ __launch_bounds__(256) void k_xaggtrans(const int* __restrict__ nlist,
        const int* __restrict__ incnt, const int* __restrict__ csr,
        const int* __restrict__ deg, const float* __restrict__ x,
        const float* __restrict__ W1, const float* __restrict__ b1,
        const float* __restrict__ W2, const int* __restrict__ counters,
        float* __restrict__ h2s) {
    __shared__ float4 sm[8][32];                     // 4 KB partials
    __shared__ float xaggL[F_IN];                    // 512 B aggregate
    __shared__ float p2[4 * HID];                    // 1 KB W1 partials
    int ncnt = counters[2]; if (ncnt > NIDCAP) ncnt = NIDCAP;
    const int tid = threadIdx.x;
    const int l = tid & 31, g = tid >> 5;            // phase-1 roles
    const int f = tid & 63, gg = tid >> 6;           // phase-2 roles
    for (int nid = blockIdx.x; nid < ncnt; nid += gridDim.x) {
        int v = nlist[nid];
        int m = incnt[nid]; if (m > MAXDEG) m = MAXDEG;
        const int* cs = csr + nid * MAXDEG;
        float4 acc = make_float4(0.f, 0.f, 0.f, 0.f);
        for (int j = g; j < m; j += 8) {
            int u = cs[j];                            // 32-lane broadcast
            float du = dinv_of(deg[u]);
            float4 xr = ((const float4*)(x + (size_t)u * F_IN))[l]; // 512B row
            acc.x += du * xr.x; acc.y += du * xr.y;
            acc.z += du * xr.z; acc.w += du * xr.w;
        }
        sm[g][l] = acc;
        __syncthreads();
        if (tid < 32) {                               // reduce + self-loop term
            float4 tot = make_float4(0.f, 0.f, 0.f, 0.f);
#pragma unroll
            for (int k = 0; k < 8; ++k) {
                float4 p = sm[k][tid];
                tot.x += p.x; tot.y += p.y; tot.z += p.z; tot.w += p.w;
            }
            float dv = dinv_of(deg[v]);
            float4 xv = ((const float4*)(x + (size_t)v * F_IN))[tid];
            float4 r;
            r.x = dv * tot.x + dv * dv * xv.x;
            r.y = dv * tot.y + dv * dv * xv.y;
            r.z = dv * tot.z + dv * dv * xv.z;
            r.w = dv * tot.w + dv * dv * xv.w;
            ((float4*)xaggL)[tid] = r;
        }
        __syncthreads();
        // phase 2: h1[f] = sum_k xaggL[k] * W1[k][f]; 4 k-slices of 32
        float a = 0.f;
#pragma unroll
        for (int k0 = 0; k0 < 32; ++k0) {
            int k = gg * 32 + k0;
            a += xaggL[k] * W1[(size_t)k * HID + f];  // coalesced, L1/L2-hot
        }
        p2[gg * HID + f] = a;
        __syncthreads();
        if (tid < HID) {
            float h = p2[tid] + p2[HID + tid] + p2[2 * HID + tid] + p2[3 * HID + tid] + b1[tid];
            float cc = fmaxf(h, 0.f) * W2[tid];
#pragma unroll
            for (int off = 32; off > 0; off >>= 1) cc += __shfl_down(cc, off, 64);
            if (tid == 0) h2s[nid] = cc;
        }
        __syncthreads();
    }
}

// layer-2 aggregation over ~2k big-dst edges + fused self-loop/b2 term
__global__ void k_agg2(const int2* __restrict__ l2list, const int* __restrict__ counters,
                       const int* __restrict__ deg, const float* __restrict__ h2s,
                       const int* __restrict__ batch, const int* __restrict__ nlist,
                       const int* __restrict__ nid_of, const float* __restrict__ b2,
                       float* __restrict__ out) {
    if (blockIdx.x == 0 && threadIdx.x < NGRAPH) {   // big nodes have nid 0..63
        int v = nlist[threadIdx.x];
        float di = dinv_of(deg[v]);
        atomicAdd(&out[batch[v]], di * di * h2s[threadIdx.x] + b2[0]);
    }
    int tid = blockIdx.x * 256 + threadIdx.x;
    int nt  = gridDim.x * 256;
    int n   = counters[1];
    if (n > L2CAP) n = L2CAP;
    for (int i = tid; i < n; i += nt) {
        int2 e = l2list[i];
        float dx = dinv_of(deg[e.x]);
        float dy = dinv_of(deg[e.y]);
        atomicAdd(&out[batch[e.y]], dx * dy * h2s[nid_of[e.x]]);
    }
}

extern "C" void kernel_launch(void* const* d_in, const int* in_sizes, int n_in,
                              void* d_out, int out_size, void* d_ws, size_t ws_size,
                              hipStream_t stream) {
    const float* x     = (const float*)d_in[0];
    const int*   eidx  = (const int*)d_in[1];
    const int*   src   = eidx;
    const int*   dst   = eidx + N_EDGES;
    const int*   batch = (const int*)d_in[2];
    const float* W1    = (const float*)d_in[3];
    const float* b1    = (const float*)d_in[4];
    const float* W2    = (const float*)d_in[5];
    const float* b2    = (const float*)d_in[6];
    float*       out   = (float*)d_out;

    // ---- workspace layout: zeroed region first (~0.45 MB) ----
    char* ws = (char*)d_ws;
    size_t off = 0;
    int*      counters = (int*)(ws + off);      off += 256;
    int*      bcnt     = (int*)(ws + off);      off += 1024;               // NBUK padded
    unsigned* nmask    = (unsigned*)(ws + off); off += NWORDS * 4;         // 12.8 KB
    unsigned* bigmask  = (unsigned*)(ws + off); off += NWORDS * 4;
    int*      incnt    = (int*)(ws + off);      off += NIDCAP * 4;
    int*      deg      = (int*)(ws + off);      off += (size_t)N_NODES * 4; // 0.4 MB
    size_t zero_bytes = off;
    int*      nid_of   = (int*)(ws + off);      off += (size_t)N_NODES * 4;
    int*      nlist    = (int*)(ws + off);      off += (size_t)NIDCAP * 4;
    float*    h2s      = (float*)(ws + off);    off += (size_t)NIDCAP * 4;
    int2*     l2list   = (int2*)(ws + off);     off += (size_t)L2CAP * 8;
    int*      csr      = (int*)(ws + off);      off += (size_t)NIDCAP * MAXDEG * 4; // 1.6 MB
    unsigned* plist    = (unsigned*)(ws + off); off += (size_t)NBUK * BCAP * 4;     // 14.5 MB
    if (off > ws_size) return;  // visible validation failure if ws too small

    hipMemsetAsync(d_ws, 0, zero_bytes, stream);

    const int BN = (N_NODES + 255) / 256;

    k_init<<<BN, 256, 0, stream>>>(batch, bigmask, nmask, nid_of, nlist, counters, out);
    k_partA<<<NBLK_A, 256, 0, stream>>>(src, dst, bigmask, nmask, plist, bcnt, l2list, counters);
    k_buildnid<<<(NWORDS + 255) / 256, 256, 0, stream>>>(nmask, bigmask, nid_of, nlist, counters);
    k_partB<<<NBUK * SLICES, 256, 0, stream>>>(plist, bcnt, nmask, nid_of, incnt, csr, deg);
    k_xaggtrans<<<NBLK_X, 256, 0, stream>>>(nlist, incnt, csr, deg, x, W1, b1, W2, counters, h2s);
    k_agg2<<<8, 256, 0, stream>>>(l2list, counters, deg, h2s, batch, nlist, nid_of, b2, out);
}